// Round 10
// baseline (2574.992 us; speedup 1.0000x reference)
//
#include <hip/hip_runtime.h>
#include <hip/hip_bf16.h>
#include <cstddef>
#include <cstdint>

#define NN 2048      // nodes (M and K of the big GEMMs)
#define CIN 2
#define HH 32        // hidden
#define EMB 16
#define HOR 12
#define BB 32        // batch
#define TT 16        // time steps
#define GC 128       // 4*HH gate channels
#define XCOLS 1024   // B*T*C
#define HCOLS 1024   // B*H  (GEMM N dim)
#define KSPLIT 4
#define KS (NN / KSPLIT)          // 512 per k-slice
#define NIT (KS / 32)             // 16 K-iterations (BK=32)
#define CSZ ((size_t)NN * HCOLS)  // one partial C: 2M floats
#define NBLK 512                  // persistent grid size (2 blocks/CU, LDS-pinned)

typedef __attribute__((ext_vector_type(8))) _Float16 f16x8;
typedef __attribute__((ext_vector_type(16))) float f32x16;
typedef unsigned short u16;

// ---------------------------------------------------------------------------
// Kernel 1: A = softmax(relu(E1 @ E2^T)) -> A2 fp16 [row][k]
// ---------------------------------------------------------------------------
__global__ __launch_bounds__(256) void adj_softmax(const float* __restrict__ E1,
                                                   const float* __restrict__ E2,
                                                   _Float16* __restrict__ A2) {
    const int i = blockIdx.x;
    __shared__ float red[256];
    float e1[EMB];
#pragma unroll
    for (int k = 0; k < EMB; ++k) e1[k] = E1[i * EMB + k];

    float s[8];
    float mx = -1e30f;
#pragma unroll
    for (int q = 0; q < 8; ++q) {
        const int j = q * 256 + threadIdx.x;
        float d = 0.f;
#pragma unroll
        for (int k = 0; k < EMB; ++k) d += e1[k] * E2[j * EMB + k];
        d = fmaxf(d, 0.0f);
        s[q] = d;
        mx = fmaxf(mx, d);
    }
    red[threadIdx.x] = mx;
    __syncthreads();
    for (int off = 128; off > 0; off >>= 1) {
        if (threadIdx.x < off) red[threadIdx.x] = fmaxf(red[threadIdx.x], red[threadIdx.x + off]);
        __syncthreads();
    }
    mx = red[0];
    __syncthreads();

    float sum = 0.f;
#pragma unroll
    for (int q = 0; q < 8; ++q) { s[q] = expf(s[q] - mx); sum += s[q]; }
    red[threadIdx.x] = sum;
    __syncthreads();
    for (int off = 128; off > 0; off >>= 1) {
        if (threadIdx.x < off) red[threadIdx.x] += red[threadIdx.x + off];
        __syncthreads();
    }
    const float inv = 1.0f / red[0];
#pragma unroll
    for (int q = 0; q < 8; ++q)
        A2[(size_t)i * NN + q * 256 + threadIdx.x] = (_Float16)(s[q] * inv);
}

// ---------------------------------------------------------------------------
// Kernel 2: B2x[col][s][node] fp16 hi/lo split of x (col = (b*T+t)*C + c).
// ---------------------------------------------------------------------------
__global__ __launch_bounds__(256) void transpose_x(const float* __restrict__ x,
                                                   _Float16* __restrict__ B2x) {
    const int idx = blockIdx.x * 256 + threadIdx.x;
    const int col = idx >> 11;
    const int j   = idx & (NN - 1);
    const int bt  = col >> 1;
    const int c   = col & 1;
    const float v = x[((size_t)bt * NN + j) * CIN + c];
    const _Float16 hi = (_Float16)v;
    const _Float16 lo = (_Float16)(v - (float)hi);
    const size_t base = (size_t)col * 4096 + j;
    B2x[base] = hi; B2x[base + 2048] = lo;
}

// ---------------------------------------------------------------------------
// Kernel 3: x-path fp16 GEMM (32x32x16), hi+lo 2-product, pipelined LDS dbuf.
// Block 128x128, 4 waves each 64x64 (2x2 accs of 32x32), BK=32, KSPLIT=4.
// ---------------------------------------------------------------------------
__global__ __launch_bounds__(256, 2) void gemm_x(const _Float16* __restrict__ A2,
                                                 const _Float16* __restrict__ B2,
                                                 float* __restrict__ Cp) {
    constexpr int BSTR = 4096;
    constexpr int BUF  = 8192 + 16384;
    __shared__ char smem[2 * BUF];
    const int tid  = threadIdx.x;
    const int w    = tid >> 6;
    const int lane = tid & 63;
    const int m0 = blockIdx.y * 128;
    const int n0 = blockIdx.x * 128;
    const int k0 = blockIdx.z * KS;

    const _Float16 *gpa0, *gpa1, *gpb0, *gpb1, *gpc0, *gpc1;
    int lda0, lda1, ldb0, ldb1, ldc0, ldc1;
    {
        int cid, ko, row;
        cid = tid;       ko = cid >> 7; row = cid & 127;
        gpa0 = A2 + (size_t)(m0 + row) * 2048 + k0 + ko * 8;
        lda0 = ko * 2048 + row * 16;
        cid = tid + 256; ko = cid >> 7; row = cid & 127;
        gpa1 = A2 + (size_t)(m0 + row) * 2048 + k0 + ko * 8;
        lda1 = ko * 2048 + row * 16;
        cid = tid;       ko = cid >> 7; row = cid & 127;
        gpb0 = B2 + (size_t)(n0 + row) * BSTR + k0 + ko * 8;
        ldb0 = 8192 + ko * 2048 + row * 16;
        cid = tid + 256; ko = cid >> 7; row = cid & 127;
        gpb1 = B2 + (size_t)(n0 + row) * BSTR + k0 + ko * 8;
        ldb1 = 8192 + ko * 2048 + row * 16;
        gpc0 = gpb0 + 2048; ldc0 = ldb0 + 8192;
        gpc1 = gpb1 + 2048; ldc1 = ldb1 + 8192;
    }

    const int lrow = lane & 31, lg = lane >> 5;
    const int wr = (w >> 1) * 64;
    const int wc = (w & 1) * 64;
    const int aoff00 = (0 * 2 + lg) * 2048 + (wr +  0 + lrow) * 16;
    const int aoff01 = (1 * 2 + lg) * 2048 + (wr +  0 + lrow) * 16;
    const int aoff10 = (0 * 2 + lg) * 2048 + (wr + 32 + lrow) * 16;
    const int aoff11 = (1 * 2 + lg) * 2048 + (wr + 32 + lrow) * 16;
    const int boff00 = 8192 + (0 * 2 + lg) * 2048 + (wc +  0 + lrow) * 16;
    const int boff01 = 8192 + (1 * 2 + lg) * 2048 + (wc +  0 + lrow) * 16;
    const int boff10 = 8192 + (0 * 2 + lg) * 2048 + (wc + 32 + lrow) * 16;
    const int boff11 = 8192 + (1 * 2 + lg) * 2048 + (wc + 32 + lrow) * 16;

    f32x16 acc00 = (f32x16)(0.0f), acc01 = (f32x16)(0.0f);
    f32x16 acc10 = (f32x16)(0.0f), acc11 = (f32x16)(0.0f);

    uint4 Xa0, Xa1, Xb0, Xb1, Xc0, Xc1;
    uint4 Ya0, Ya1, Yb0, Yb1, Yc0, Yc1;

#define LOADSET(P)                                                             \
    P##a0 = *(const uint4*)gpa0; gpa0 += 32;                                   \
    P##a1 = *(const uint4*)gpa1; gpa1 += 32;                                   \
    P##b0 = *(const uint4*)gpb0; gpb0 += 32;                                   \
    P##b1 = *(const uint4*)gpb1; gpb1 += 32;                                   \
    P##c0 = *(const uint4*)gpc0; gpc0 += 32;                                   \
    P##c1 = *(const uint4*)gpc1; gpc1 += 32;

#define STORESET(P, SB)                                                        \
    *(uint4*)((SB) + lda0) = P##a0;                                            \
    *(uint4*)((SB) + lda1) = P##a1;                                            \
    *(uint4*)((SB) + ldb0) = P##b0;                                            \
    *(uint4*)((SB) + ldb1) = P##b1;                                            \
    *(uint4*)((SB) + ldc0) = P##c0;                                            \
    *(uint4*)((SB) + ldc1) = P##c1;

#define COMPUTE(BUFI) do {                                                     \
    const char* sb = smem + (BUFI) * BUF;                                      \
    f16x8 fa00 = *(const f16x8*)(sb + aoff00);                                 \
    f16x8 fa01 = *(const f16x8*)(sb + aoff01);                                 \
    f16x8 fa10 = *(const f16x8*)(sb + aoff10);                                 \
    f16x8 fa11 = *(const f16x8*)(sb + aoff11);                                 \
    f16x8 fb00 = *(const f16x8*)(sb + boff00);                                 \
    f16x8 fb01 = *(const f16x8*)(sb + boff01);                                 \
    f16x8 fb10 = *(const f16x8*)(sb + boff10);                                 \
    f16x8 fb11 = *(const f16x8*)(sb + boff11);                                 \
    acc00 = __builtin_amdgcn_mfma_f32_32x32x16_f16(fa00, fb00, acc00, 0, 0, 0);\
    acc01 = __builtin_amdgcn_mfma_f32_32x32x16_f16(fa00, fb10, acc01, 0, 0, 0);\
    acc10 = __builtin_amdgcn_mfma_f32_32x32x16_f16(fa10, fb00, acc10, 0, 0, 0);\
    acc11 = __builtin_amdgcn_mfma_f32_32x32x16_f16(fa10, fb10, acc11, 0, 0, 0);\
    acc00 = __builtin_amdgcn_mfma_f32_32x32x16_f16(fa01, fb01, acc00, 0, 0, 0);\
    acc01 = __builtin_amdgcn_mfma_f32_32x32x16_f16(fa01, fb11, acc01, 0, 0, 0);\
    acc10 = __builtin_amdgcn_mfma_f32_32x32x16_f16(fa11, fb01, acc10, 0, 0, 0);\
    acc11 = __builtin_amdgcn_mfma_f32_32x32x16_f16(fa11, fb11, acc11, 0, 0, 0);\
    f16x8 fc00 = *(const f16x8*)(sb + boff00 + 8192);                          \
    f16x8 fc01 = *(const f16x8*)(sb + boff01 + 8192);                          \
    f16x8 fc10 = *(const f16x8*)(sb + boff10 + 8192);                          \
    f16x8 fc11 = *(const f16x8*)(sb + boff11 + 8192);                          \
    acc00 = __builtin_amdgcn_mfma_f32_32x32x16_f16(fa00, fc00, acc00, 0, 0, 0);\
    acc01 = __builtin_amdgcn_mfma_f32_32x32x16_f16(fa00, fc10, acc01, 0, 0, 0);\
    acc10 = __builtin_amdgcn_mfma_f32_32x32x16_f16(fa10, fc00, acc10, 0, 0, 0);\
    acc11 = __builtin_amdgcn_mfma_f32_32x32x16_f16(fa10, fc10, acc11, 0, 0, 0);\
    acc00 = __builtin_amdgcn_mfma_f32_32x32x16_f16(fa01, fc01, acc00, 0, 0, 0);\
    acc01 = __builtin_amdgcn_mfma_f32_32x32x16_f16(fa01, fc11, acc01, 0, 0, 0);\
    acc10 = __builtin_amdgcn_mfma_f32_32x32x16_f16(fa11, fc01, acc10, 0, 0, 0);\
    acc11 = __builtin_amdgcn_mfma_f32_32x32x16_f16(fa11, fc11, acc11, 0, 0, 0);\
} while (0)

    LOADSET(X)
    LOADSET(Y)
#pragma unroll 1
    for (int it = 0; it < NIT; it += 2) {
        STORESET(X, smem)
        __syncthreads();
        LOADSET(X)
        COMPUTE(0);
        STORESET(Y, smem + BUF)
        __syncthreads();
        LOADSET(Y)
        COMPUTE(1);
    }
#undef LOADSET
#undef STORESET
#undef COMPUTE

    float* Cs = Cp + (size_t)blockIdx.z * CSZ;
    const int col0 = n0 + wc + lrow;
#pragma unroll
    for (int r = 0; r < 16; ++r) {
        const int rp = (r & 3) + 8 * (r >> 2) + 4 * lg;
        Cs[(size_t)(m0 + wr + rp) * HCOLS + col0]           = acc00[r];
        Cs[(size_t)(m0 + wr + rp) * HCOLS + col0 + 32]      = acc01[r];
        Cs[(size_t)(m0 + wr + 32 + rp) * HCOLS + col0]      = acc10[r];
        Cs[(size_t)(m0 + wr + 32 + rp) * HCOLS + col0 + 32] = acc11[r];
    }
}

// ---------------------------------------------------------------------------
// Kernel 3b: AX = sum of KSPLIT k-slice partials (one-time, x path)
// ---------------------------------------------------------------------------
__global__ __launch_bounds__(256) void reduce_ax(const float* __restrict__ P,
                                                 float* __restrict__ AX) {
    const size_t idx = (size_t)blockIdx.x * 256 + threadIdx.x;
    const float4* P4 = (const float4*)P;
    const size_t q = CSZ / 4;
    float4 a = P4[idx], b = P4[idx + q], c = P4[idx + 2 * q], d = P4[idx + 3 * q];
    float4 r;
    r.x = a.x + b.x + c.x + d.x;
    r.y = a.y + b.y + c.y + d.y;
    r.z = a.z + b.z + c.z + d.z;
    r.w = a.w + b.w + c.w + d.w;
    ((float4*)AX)[idx] = r;
}

// ---------------------------------------------------------------------------
// Kernel 3c: weight prep. Whr[k][h][g] = Wh[k][g*32+h]; Wxr[c][h][g]; bfold.
// ---------------------------------------------------------------------------
__global__ __launch_bounds__(256) void prep_weights(const float* __restrict__ Wx,
                                                    const float* __restrict__ bx,
                                                    const float* __restrict__ Wh,
                                                    const float* __restrict__ bh,
                                                    float* __restrict__ Whr,
                                                    float* __restrict__ Wxr,
                                                    float* __restrict__ bfold) {
    const int tid = threadIdx.x;
#pragma unroll
    for (int r = 0; r < 16; ++r) {
        const int idx = tid * 16 + r;           // 4096
        const int k = idx >> 7, rem = idx & 127;
        const int h = rem >> 2, g = rem & 3;
        Whr[idx] = Wh[k * GC + g * HH + h];
    }
    {
        const int idx = tid;                    // 256
        const int c = idx >> 7, rem = idx & 127;
        const int h = rem >> 2, g = rem & 3;
        Wxr[idx] = Wx[c * GC + g * HH + h];
    }
    if (tid < 128) {
        const int h = tid >> 2, g = tid & 3;
        bfold[tid] = bx[g * HH + h] + bh[g * HH + h];
    }
}

// ---------------------------------------------------------------------------
// Manual grid barrier (monotonic counter, agent-scope acq_rel).
// Safe because all NBLK blocks are co-resident (59.6KB LDS -> exactly 2/CU).
// Bounded spin converts any residual deadlock into a wrong-answer fail.
// ---------------------------------------------------------------------------
__device__ __forceinline__ void grid_barrier(unsigned* bar) {
    __syncthreads();
    if (threadIdx.x == 0) {
        const unsigned old = __hip_atomic_fetch_add(bar, 1u, __ATOMIC_ACQ_REL,
                                                    __HIP_MEMORY_SCOPE_AGENT);
        const unsigned target = (old / NBLK + 1) * NBLK;
        unsigned spins = 0;
        while (__hip_atomic_load(bar, __ATOMIC_ACQUIRE, __HIP_MEMORY_SCOPE_AGENT) < target
               && spins < (1u << 27)) {
            __builtin_amdgcn_s_sleep(2);
            ++spins;
        }
    }
    __syncthreads();
}

// ---------------------------------------------------------------------------
// Kernel 4: PERSISTENT kernel - the whole 16-step recurrence (plain launch).
// 512 blocks x 256 thr (2 blocks/CU co-resident, pinned by LDS). Per step:
//   phase A (t>0): gemm tile P[z] = A[.][z] * hT[z-slice]  (r8 structure)
//   grid_barrier
//   phase B: gate/LSTM update for 64 nodes x 2 batches; c-state in REGISTERS,
//            LSTM weights LDS-resident across all steps.
//   grid_barrier
// ---------------------------------------------------------------------------
__global__ __launch_bounds__(256, 2) void recurrent_loop(
        const _Float16* __restrict__ A2,
        const float* __restrict__ AX,
        float* __restrict__ P,
        const float* __restrict__ Whr,
        const float* __restrict__ Wxr,
        const float* __restrict__ bfold,
        float* __restrict__ h32,
        _Float16* __restrict__ hT,
        unsigned* bar) {
    constexpr int GBUF = 16384;                 // gemm LDS buffer (A 8K + B 8K)
    __shared__ char smem[2 * GBUF];
    __shared__ float whr[4096];
    __shared__ float wxr[256];
    __shared__ float bfl[128];
    __shared__ float ah_s[64][33];
    __shared__ float axs[2][64];

    const int tid = threadIdx.x;
    const int bid = blockIdx.x;

    // ---- stage LSTM weights ONCE for all steps ----
#pragma unroll
    for (int r = 0; r < 4; ++r)
        *(float4*)&whr[tid * 4 + r * 1024] = *(const float4*)&Whr[tid * 4 + r * 1024];
    if (tid < 64) *(float4*)&wxr[tid * 4] = *(const float4*)&Wxr[tid * 4];
    if (tid < 32) *(float4*)&bfl[tid * 4] = *(const float4*)&bfold[tid * 4];
    __syncthreads();

    // ---- gemm tile assignment: bid -> (z, my, mx) : 4 x 16 x 8 ----
    const int z  = bid & 3;
    const int my = (bid >> 2) & 15;
    const int mx = bid >> 6;                    // 0..7
    const int m0 = my * 128, n0 = mx * 128, k0 = z * KS;
    const int w = tid >> 6, lane = tid & 63;

    const _Float16 *gA0, *gA1, *gB0, *gB1;
    int lda0, lda1, ldb0, ldb1;
    {
        int cid, ko, row;
        cid = tid;       ko = cid >> 7; row = cid & 127;
        gA0 = A2 + (size_t)(m0 + row) * 2048 + k0 + ko * 8;
        lda0 = ko * 2048 + row * 16;
        cid = tid + 256; ko = cid >> 7; row = cid & 127;
        gA1 = A2 + (size_t)(m0 + row) * 2048 + k0 + ko * 8;
        lda1 = ko * 2048 + row * 16;
        cid = tid;       ko = cid >> 7; row = cid & 127;
        gB0 = hT + (size_t)(n0 + row) * 2048 + k0 + ko * 8;
        ldb0 = 8192 + ko * 2048 + row * 16;
        cid = tid + 256; ko = cid >> 7; row = cid & 127;
        gB1 = hT + (size_t)(n0 + row) * 2048 + k0 + ko * 8;
        ldb1 = 8192 + ko * 2048 + row * 16;
    }
    const int lrow = lane & 31, lg = lane >> 5;
    const int wr = (w >> 1) * 64;
    const int wc = (w & 1) * 64;
    const int aoff00 = (0 * 2 + lg) * 2048 + (wr +  0 + lrow) * 16;
    const int aoff01 = (1 * 2 + lg) * 2048 + (wr +  0 + lrow) * 16;
    const int aoff10 = (0 * 2 + lg) * 2048 + (wr + 32 + lrow) * 16;
    const int aoff11 = (1 * 2 + lg) * 2048 + (wr + 32 + lrow) * 16;
    const int boff00 = 8192 + (0 * 2 + lg) * 2048 + (wc +  0 + lrow) * 16;
    const int boff01 = 8192 + (1 * 2 + lg) * 2048 + (wc +  0 + lrow) * 16;
    const int boff10 = 8192 + (0 * 2 + lg) * 2048 + (wc + 32 + lrow) * 16;
    const int boff11 = 8192 + (1 * 2 + lg) * 2048 + (wc + 32 + lrow) * 16;

    // ---- gate assignment: bid -> (slab 32, batch-pair 16) ----
    const int n0g  = (bid >> 4) * 64;
    const int bpr2 = (bid & 15) * 2;
    const int nl = tid & 63;
    const int hq = tid >> 6;

    float creg[2][8];                            // c-state in registers
#pragma unroll
    for (int bi = 0; bi < 2; ++bi)
#pragma unroll
        for (int u = 0; u < 8; ++u) creg[bi][u] = 0.0f;

#pragma unroll 1
    for (int t = 0; t < TT; ++t) {
        // ================= phase A: gemm P[z] = A * hT ====================
        if (t > 0) {
            const _Float16 *gpa0 = gA0, *gpa1 = gA1, *gpb0 = gB0, *gpb1 = gB1;
            f32x16 acc00 = (f32x16)(0.0f), acc01 = (f32x16)(0.0f);
            f32x16 acc10 = (f32x16)(0.0f), acc11 = (f32x16)(0.0f);
            uint4 Xa0, Xa1, Xb0, Xb1, Ya0, Ya1, Yb0, Yb1;

#define GLOADSET(Q)                                                            \
    Q##a0 = *(const uint4*)gpa0; gpa0 += 32;                                   \
    Q##a1 = *(const uint4*)gpa1; gpa1 += 32;                                   \
    Q##b0 = *(const uint4*)gpb0; gpb0 += 32;                                   \
    Q##b1 = *(const uint4*)gpb1; gpb1 += 32;
#define GSTORESET(Q, SB)                                                       \
    *(uint4*)((SB) + lda0) = Q##a0;                                            \
    *(uint4*)((SB) + lda1) = Q##a1;                                            \
    *(uint4*)((SB) + ldb0) = Q##b0;                                            \
    *(uint4*)((SB) + ldb1) = Q##b1;
#define GCOMPUTE(BUFI) do {                                                    \
    const char* sb = smem + (BUFI) * GBUF;                                     \
    f16x8 fa00 = *(const f16x8*)(sb + aoff00);                                 \
    f16x8 fa01 = *(const f16x8*)(sb + aoff01);                                 \
    f16x8 fa10 = *(const f16x8*)(sb + aoff10);                                 \
    f16x8 fa11 = *(const f16x8*)(sb + aoff11);                                 \
    f16x8 fb00 = *(const f16x8*)(sb + boff00);                                 \
    f16x8 fb01 = *(const f16x8*)(sb + boff01);                                 \
    f16x8 fb10 = *(const f16x8*)(sb + boff10);                                 \
    f16x8 fb11 = *(const f16x8*)(sb + boff11);                                 \
    acc00 = __builtin_amdgcn_mfma_f32_32x32x16_f16(fa00, fb00, acc00, 0, 0, 0);\
    acc01 = __builtin_amdgcn_mfma_f32_32x32x16_f16(fa00, fb10, acc01, 0, 0, 0);\
    acc10 = __builtin_amdgcn_mfma_f32_32x32x16_f16(fa10, fb00, acc10, 0, 0, 0);\
    acc11 = __builtin_amdgcn_mfma_f32_32x32x16_f16(fa10, fb10, acc11, 0, 0, 0);\
    acc00 = __builtin_amdgcn_mfma_f32_32x32x16_f16(fa01, fb01, acc00, 0, 0, 0);\
    acc01 = __builtin_amdgcn_mfma_f32_32x32x16_f16(fa01, fb11, acc01, 0, 0, 0);\
    acc10 = __builtin_amdgcn_mfma_f32_32x32x16_f16(fa11, fb01, acc10, 0, 0, 0);\
    acc11 = __builtin_amdgcn_mfma_f32_32x32x16_f16(fa11, fb11, acc11, 0, 0, 0);\
} while (0)

            GLOADSET(X)
            GLOADSET(Y)
#pragma unroll 1
            for (int it = 0; it < NIT; it += 2) {
                GSTORESET(X, smem)
                __syncthreads();
                GLOADSET(X)
                GCOMPUTE(0);
                GSTORESET(Y, smem + GBUF)
                __syncthreads();
                GLOADSET(Y)
                GCOMPUTE(1);
            }
#undef GLOADSET
#undef GSTORESET
#undef GCOMPUTE
            float* Cs = P + (size_t)z * CSZ;
            const int col0 = n0 + wc + lrow;
#pragma unroll
            for (int r = 0; r < 16; ++r) {
                const int rp = (r & 3) + 8 * (r >> 2) + 4 * lg;
                Cs[(size_t)(m0 + wr + rp) * HCOLS + col0]           = acc00[r];
                Cs[(size_t)(m0 + wr + rp) * HCOLS + col0 + 32]      = acc01[r];
                Cs[(size_t)(m0 + wr + 32 + rp) * HCOLS + col0]      = acc10[r];
                Cs[(size_t)(m0 + wr + 32 + rp) * HCOLS + col0 + 32] = acc11[r];
            }
            grid_barrier(bar);
        }

        // ================= phase B: gates + cell update ====================
#pragma unroll 1
        for (int bi = 0; bi < 2; ++bi) {
            const int b = bpr2 + bi;
            if (bi) __syncthreads();
            if (t > 0) {
                const int nls = tid >> 2;
                const int kq = (tid & 3) * 8;
                float4 a0 = make_float4(0, 0, 0, 0), a1 = make_float4(0, 0, 0, 0);
#pragma unroll
                for (int s = 0; s < KSPLIT; ++s) {
                    const float* src = P + s * CSZ + (size_t)(n0g + nls) * HCOLS + b * HH + kq;
                    const float4 v0 = *(const float4*)src;
                    const float4 v1 = *(const float4*)(src + 4);
                    a0.x += v0.x; a0.y += v0.y; a0.z += v0.z; a0.w += v0.w;
                    a1.x += v1.x; a1.y += v1.y; a1.z += v1.z; a1.w += v1.w;
                }
                ah_s[nls][kq + 0] = a0.x; ah_s[nls][kq + 1] = a0.y;
                ah_s[nls][kq + 2] = a0.z; ah_s[nls][kq + 3] = a0.w;
                ah_s[nls][kq + 4] = a1.x; ah_s[nls][kq + 5] = a1.y;
                ah_s[nls][kq + 6] = a1.z; ah_s[nls][kq + 7] = a1.w;
            }
            if (tid < 128) {
                const int which = tid >> 6, nls = tid & 63;
                axs[which][nls] = AX[(size_t)(n0g + nls) * XCOLS + (b * TT + t) * CIN + which];
            }
            __syncthreads();

            const float ax0 = axs[0][nl], ax1 = axs[1][nl];
            float acc[8][4];
#pragma unroll
            for (int u = 0; u < 8; ++u) {
                const int h = hq * 8 + u;
#pragma unroll
                for (int g = 0; g < 4; ++g)
                    acc[u][g] = bfl[h * 4 + g] + ax0 * wxr[h * 4 + g] + ax1 * wxr[128 + h * 4 + g];
            }
            if (t > 0) {
                float ah_r[HH];
#pragma unroll
                for (int k = 0; k < HH; ++k) ah_r[k] = ah_s[nl][k];
#pragma unroll 4
                for (int k = 0; k < HH; ++k) {
                    const float a = ah_r[k];
#pragma unroll
                    for (int u = 0; u < 8; ++u) {
                        const float* wp = &whr[(k * HH + hq * 8 + u) * 4];
                        acc[u][0] += a * wp[0];
                        acc[u][1] += a * wp[1];
                        acc[u][2] += a * wp[2];
                        acc[u][3] += a * wp[3];
                    }
                }
            }

            float hn[8];
#pragma unroll
            for (int u = 0; u < 8; ++u) {
                const float i_ = 1.0f / (1.0f + expf(-acc[u][0]));
                const float f_ = 1.0f / (1.0f + expf(-acc[u][1]));
                const float o_ = 1.0f / (1.0f + expf(-acc[u][2]));
                const float g_ = tanhf(acc[u][3]);
                const float c_t = f_ * creg[bi][u] + i_ * g_;
                creg[bi][u] = c_t;
                hn[u] = o_ * tanhf(c_t);
            }
#pragma unroll
            for (int u = 0; u < 8; ++u)
                hT[(size_t)(b * HH + hq * 8 + u) * 2048 + n0g + nl] = (_Float16)hn[u];
            if (t == TT - 1) {
                const size_t off = (size_t)(n0g + nl) * HCOLS + b * HH + hq * 8;
                *(float4*)(h32 + off)     = make_float4(hn[0], hn[1], hn[2], hn[3]);
                *(float4*)(h32 + off + 4) = make_float4(hn[4], hn[5], hn[6], hn[7]);
            }
        }
        if (t < TT - 1) grid_barrier(bar);
    }
}

// ---------------------------------------------------------------------------
// Kernel 5: out[b][th][n] = bp[th] + sum_k h[n][b*H+k] * Wp[k][th]
// ---------------------------------------------------------------------------
__global__ __launch_bounds__(256) void head_kernel(const float* __restrict__ h,
                                                   const float* __restrict__ Wp,
                                                   const float* __restrict__ bp,
                                                   float* __restrict__ out) {
    const int idx = blockIdx.x * 256 + threadIdx.x;
    const int b = idx >> 11;
    const int n = idx & (NN - 1);
    float hv[HH];
    const float* hp = h + (size_t)n * HCOLS + b * HH;
#pragma unroll
    for (int k = 0; k < HH; ++k) hv[k] = hp[k];
#pragma unroll
    for (int th = 0; th < HOR; ++th) {
        float acc = bp[th];
#pragma unroll
        for (int k = 0; k < HH; ++k) acc += hv[k] * Wp[k * HOR + th];
        out[((size_t)b * HOR + th) * NN + n] = acc;
    }
}

// ---------------------------------------------------------------------------
extern "C" void kernel_launch(void* const* d_in, const int* in_sizes, int n_in,
                              void* d_out, int out_size, void* d_ws, size_t ws_size,
                              hipStream_t stream) {
    const float* x  = (const float*)d_in[0];
    const float* E1 = (const float*)d_in[1];
    const float* E2 = (const float*)d_in[2];
    const float* Wx = (const float*)d_in[3];
    const float* bx = (const float*)d_in[4];
    const float* Wh = (const float*)d_in[5];
    const float* bh = (const float*)d_in[6];
    const float* Wp = (const float*)d_in[7];
    const float* bp = (const float*)d_in[8];

    char* ws = (char*)d_ws;
    _Float16* A2  = (_Float16*)(ws);                    //  8 MB  [2048][2048]
    _Float16* B2x = (_Float16*)(ws + ( 8ull << 20));    //  8 MB  [1024][2][2048]
    _Float16* hT  = (_Float16*)(ws + (16ull << 20));    //  4 MB  [1024][2048]
    float* P    = (float*)(ws + (20ull << 20));         // 32 MB  (4 k-slice partials)
    float* AX   = (float*)(ws + (52ull << 20));         //  8 MB
    float* h32  = (float*)(ws + (68ull << 20));         //  8 MB
    float* Whr  = (float*)(ws + (76ull << 20));         // 16 KB
    float* Wxr  = (float*)(ws + (76ull << 20) + 65536);
    float* bfold= (float*)(ws + (76ull << 20) + 131072);
    unsigned* bar = (unsigned*)(ws + (77ull << 20));    // grid-barrier counter

    hipMemsetAsync(bar, 0, 256, stream);                // zero barrier counter

    adj_softmax<<<NN, 256, 0, stream>>>(E1, E2, A2);
    transpose_x<<<(XCOLS * NN) / 256, 256, 0, stream>>>(x, B2x);
    prep_weights<<<1, 256, 0, stream>>>(Wx, bx, Wh, bh, Whr, Wxr, bfold);

    dim3 gg(HCOLS / 128, NN / 128, KSPLIT);   // 8 x 16 x 4 = 512 blocks
    gemm_x<<<gg, 256, 0, stream>>>(A2, B2x, P);          // x path: hi+lo
    reduce_ax<<<(int)(CSZ / 4 / 256), 256, 0, stream>>>(P, AX);

    // whole recurrence: one persistent kernel (512 blocks = 2/CU, LDS-pinned)
    recurrent_loop<<<NBLK, 256, 0, stream>>>(A2, AX, P, Whr, Wxr, bfold, h32, hT, bar);

    head_kernel<<<(BB * NN) / 256, 256, 0, stream>>>(h32, Wp, bp, (float*)d_out);
}

// Round 11
// 1212.400 us; speedup vs baseline: 2.1239x; 2.1239x over previous
//
#include <hip/hip_runtime.h>
#include <hip/hip_bf16.h>
#include <cstddef>
#include <cstdint>

#define NN 2048      // nodes (M and K of the big GEMMs)
#define CIN 2
#define HH 32        // hidden
#define EMB 16
#define HOR 12
#define BB 32        // batch
#define TT 16        // time steps
#define GC 128       // 4*HH gate channels
#define XCOLS 1024   // B*T*C
#define HCOLS 1024   // B*H
#define KSPLIT 4     // x-path gemm only
#define KS (NN / KSPLIT)
#define CSZ ((size_t)NN * HCOLS)
#define NG 16        // chain groups (2 batches each)
#define GBLK 32      // blocks per group
#define CNIT 32      // chain gemm K-iters (BK=64, K=2048)

typedef __attribute__((ext_vector_type(8))) _Float16 f16x8;
typedef __attribute__((ext_vector_type(16))) float f32x16;

// ---------------------------------------------------------------------------
// Kernel 1: A = softmax(relu(E1 @ E2^T)) -> A2 fp16 [row][k]
// ---------------------------------------------------------------------------
__global__ __launch_bounds__(256) void adj_softmax(const float* __restrict__ E1,
                                                   const float* __restrict__ E2,
                                                   _Float16* __restrict__ A2) {
    const int i = blockIdx.x;
    __shared__ float red[256];
    float e1[EMB];
#pragma unroll
    for (int k = 0; k < EMB; ++k) e1[k] = E1[i * EMB + k];

    float s[8];
    float mx = -1e30f;
#pragma unroll
    for (int q = 0; q < 8; ++q) {
        const int j = q * 256 + threadIdx.x;
        float d = 0.f;
#pragma unroll
        for (int k = 0; k < EMB; ++k) d += e1[k] * E2[j * EMB + k];
        d = fmaxf(d, 0.0f);
        s[q] = d;
        mx = fmaxf(mx, d);
    }
    red[threadIdx.x] = mx;
    __syncthreads();
    for (int off = 128; off > 0; off >>= 1) {
        if (threadIdx.x < off) red[threadIdx.x] = fmaxf(red[threadIdx.x], red[threadIdx.x + off]);
        __syncthreads();
    }
    mx = red[0];
    __syncthreads();

    float sum = 0.f;
#pragma unroll
    for (int q = 0; q < 8; ++q) { s[q] = expf(s[q] - mx); sum += s[q]; }
    red[threadIdx.x] = sum;
    __syncthreads();
    for (int off = 128; off > 0; off >>= 1) {
        if (threadIdx.x < off) red[threadIdx.x] += red[threadIdx.x + off];
        __syncthreads();
    }
    const float inv = 1.0f / red[0];
#pragma unroll
    for (int q = 0; q < 8; ++q)
        A2[(size_t)i * NN + q * 256 + threadIdx.x] = (_Float16)(s[q] * inv);
}

// ---------------------------------------------------------------------------
// Kernel 2: B2x[col][s][node] fp16 hi/lo split of x (col = (b*T+t)*C + c).
// ---------------------------------------------------------------------------
__global__ __launch_bounds__(256) void transpose_x(const float* __restrict__ x,
                                                   _Float16* __restrict__ B2x) {
    const int idx = blockIdx.x * 256 + threadIdx.x;
    const int col = idx >> 11;
    const int j   = idx & (NN - 1);
    const int bt  = col >> 1;
    const int c   = col & 1;
    const float v = x[((size_t)bt * NN + j) * CIN + c];
    const _Float16 hi = (_Float16)v;
    const _Float16 lo = (_Float16)(v - (float)hi);
    const size_t base = (size_t)col * 4096 + j;
    B2x[base] = hi; B2x[base + 2048] = lo;
}

// ---------------------------------------------------------------------------
// Kernel 3: x-path fp16 GEMM (32x32x16), hi+lo 2-product, pipelined LDS dbuf.
// Block 128x128, 4 waves each 64x64 (2x2 accs of 32x32), BK=32, KSPLIT=4.
// (unchanged from round 8 - proven)
// ---------------------------------------------------------------------------
__global__ __launch_bounds__(256, 2) void gemm_x(const _Float16* __restrict__ A2,
                                                 const _Float16* __restrict__ B2,
                                                 float* __restrict__ Cp) {
    constexpr int BSTR = 4096;
    constexpr int BUF  = 8192 + 16384;
    __shared__ char smem[2 * BUF];
    const int tid  = threadIdx.x;
    const int w    = tid >> 6;
    const int lane = tid & 63;
    const int m0 = blockIdx.y * 128;
    const int n0 = blockIdx.x * 128;
    const int k0 = blockIdx.z * KS;

    const _Float16 *gpa0, *gpa1, *gpb0, *gpb1, *gpc0, *gpc1;
    int lda0, lda1, ldb0, ldb1, ldc0, ldc1;
    {
        int cid, ko, row;
        cid = tid;       ko = cid >> 7; row = cid & 127;
        gpa0 = A2 + (size_t)(m0 + row) * 2048 + k0 + ko * 8;
        lda0 = ko * 2048 + row * 16;
        cid = tid + 256; ko = cid >> 7; row = cid & 127;
        gpa1 = A2 + (size_t)(m0 + row) * 2048 + k0 + ko * 8;
        lda1 = ko * 2048 + row * 16;
        cid = tid;       ko = cid >> 7; row = cid & 127;
        gpb0 = B2 + (size_t)(n0 + row) * BSTR + k0 + ko * 8;
        ldb0 = 8192 + ko * 2048 + row * 16;
        cid = tid + 256; ko = cid >> 7; row = cid & 127;
        gpb1 = B2 + (size_t)(n0 + row) * BSTR + k0 + ko * 8;
        ldb1 = 8192 + ko * 2048 + row * 16;
        gpc0 = gpb0 + 2048; ldc0 = ldb0 + 8192;
        gpc1 = gpb1 + 2048; ldc1 = ldb1 + 8192;
    }

    const int lrow = lane & 31, lg = lane >> 5;
    const int wr = (w >> 1) * 64;
    const int wc = (w & 1) * 64;
    const int aoff00 = (0 * 2 + lg) * 2048 + (wr +  0 + lrow) * 16;
    const int aoff01 = (1 * 2 + lg) * 2048 + (wr +  0 + lrow) * 16;
    const int aoff10 = (0 * 2 + lg) * 2048 + (wr + 32 + lrow) * 16;
    const int aoff11 = (1 * 2 + lg) * 2048 + (wr + 32 + lrow) * 16;
    const int boff00 = 8192 + (0 * 2 + lg) * 2048 + (wc +  0 + lrow) * 16;
    const int boff01 = 8192 + (1 * 2 + lg) * 2048 + (wc +  0 + lrow) * 16;
    const int boff10 = 8192 + (0 * 2 + lg) * 2048 + (wc + 32 + lrow) * 16;
    const int boff11 = 8192 + (1 * 2 + lg) * 2048 + (wc + 32 + lrow) * 16;

    f32x16 acc00 = (f32x16)(0.0f), acc01 = (f32x16)(0.0f);
    f32x16 acc10 = (f32x16)(0.0f), acc11 = (f32x16)(0.0f);

    uint4 Xa0, Xa1, Xb0, Xb1, Xc0, Xc1;
    uint4 Ya0, Ya1, Yb0, Yb1, Yc0, Yc1;

#define LOADSET(P)                                                             \
    P##a0 = *(const uint4*)gpa0; gpa0 += 32;                                   \
    P##a1 = *(const uint4*)gpa1; gpa1 += 32;                                   \
    P##b0 = *(const uint4*)gpb0; gpb0 += 32;                                   \
    P##b1 = *(const uint4*)gpb1; gpb1 += 32;                                   \
    P##c0 = *(const uint4*)gpc0; gpc0 += 32;                                   \
    P##c1 = *(const uint4*)gpc1; gpc1 += 32;

#define STORESET(P, SB)                                                        \
    *(uint4*)((SB) + lda0) = P##a0;                                            \
    *(uint4*)((SB) + lda1) = P##a1;                                            \
    *(uint4*)((SB) + ldb0) = P##b0;                                            \
    *(uint4*)((SB) + ldb1) = P##b1;                                            \
    *(uint4*)((SB) + ldc0) = P##c0;                                            \
    *(uint4*)((SB) + ldc1) = P##c1;

#define COMPUTE(BUFI) do {                                                     \
    const char* sb = smem + (BUFI) * BUF;                                      \
    f16x8 fa00 = *(const f16x8*)(sb + aoff00);                                 \
    f16x8 fa01 = *(const f16x8*)(sb + aoff01);                                 \
    f16x8 fa10 = *(const f16x8*)(sb + aoff10);                                 \
    f16x8 fa11 = *(const f16x8*)(sb + aoff11);                                 \
    f16x8 fb00 = *(const f16x8*)(sb + boff00);                                 \
    f16x8 fb01 = *(const f16x8*)(sb + boff01);                                 \
    f16x8 fb10 = *(const f16x8*)(sb + boff10);                                 \
    f16x8 fb11 = *(const f16x8*)(sb + boff11);                                 \
    acc00 = __builtin_amdgcn_mfma_f32_32x32x16_f16(fa00, fb00, acc00, 0, 0, 0);\
    acc01 = __builtin_amdgcn_mfma_f32_32x32x16_f16(fa00, fb10, acc01, 0, 0, 0);\
    acc10 = __builtin_amdgcn_mfma_f32_32x32x16_f16(fa10, fb00, acc10, 0, 0, 0);\
    acc11 = __builtin_amdgcn_mfma_f32_32x32x16_f16(fa10, fb10, acc11, 0, 0, 0);\
    acc00 = __builtin_amdgcn_mfma_f32_32x32x16_f16(fa01, fb01, acc00, 0, 0, 0);\
    acc01 = __builtin_amdgcn_mfma_f32_32x32x16_f16(fa01, fb11, acc01, 0, 0, 0);\
    acc10 = __builtin_amdgcn_mfma_f32_32x32x16_f16(fa11, fb01, acc10, 0, 0, 0);\
    acc11 = __builtin_amdgcn_mfma_f32_32x32x16_f16(fa11, fb11, acc11, 0, 0, 0);\
    f16x8 fc00 = *(const f16x8*)(sb + boff00 + 8192);                          \
    f16x8 fc01 = *(const f16x8*)(sb + boff01 + 8192);                          \
    f16x8 fc10 = *(const f16x8*)(sb + boff10 + 8192);                          \
    f16x8 fc11 = *(const f16x8*)(sb + boff11 + 8192);                          \
    acc00 = __builtin_amdgcn_mfma_f32_32x32x16_f16(fa00, fc00, acc00, 0, 0, 0);\
    acc01 = __builtin_amdgcn_mfma_f32_32x32x16_f16(fa00, fc10, acc01, 0, 0, 0);\
    acc10 = __builtin_amdgcn_mfma_f32_32x32x16_f16(fa10, fc00, acc10, 0, 0, 0);\
    acc11 = __builtin_amdgcn_mfma_f32_32x32x16_f16(fa10, fc10, acc11, 0, 0, 0);\
    acc00 = __builtin_amdgcn_mfma_f32_32x32x16_f16(fa01, fc01, acc00, 0, 0, 0);\
    acc01 = __builtin_amdgcn_mfma_f32_32x32x16_f16(fa01, fc11, acc01, 0, 0, 0);\
    acc10 = __builtin_amdgcn_mfma_f32_32x32x16_f16(fa11, fc01, acc10, 0, 0, 0);\
    acc11 = __builtin_amdgcn_mfma_f32_32x32x16_f16(fa11, fc11, acc11, 0, 0, 0);\
} while (0)

    LOADSET(X)
    LOADSET(Y)
#pragma unroll 1
    for (int it = 0; it < KS / 32; it += 2) {
        STORESET(X, smem)
        __syncthreads();
        LOADSET(X)
        COMPUTE(0);
        STORESET(Y, smem + BUF)
        __syncthreads();
        LOADSET(Y)
        COMPUTE(1);
    }
#undef LOADSET
#undef STORESET
#undef COMPUTE

    float* Cs = Cp + (size_t)blockIdx.z * CSZ;
    const int col0 = n0 + wc + lrow;
#pragma unroll
    for (int r = 0; r < 16; ++r) {
        const int rp = (r & 3) + 8 * (r >> 2) + 4 * lg;
        Cs[(size_t)(m0 + wr + rp) * HCOLS + col0]           = acc00[r];
        Cs[(size_t)(m0 + wr + rp) * HCOLS + col0 + 32]      = acc01[r];
        Cs[(size_t)(m0 + wr + 32 + rp) * HCOLS + col0]      = acc10[r];
        Cs[(size_t)(m0 + wr + 32 + rp) * HCOLS + col0 + 32] = acc11[r];
    }
}

// ---------------------------------------------------------------------------
// Kernel 3b: AX = sum of KSPLIT k-slice partials (one-time, x path)
// ---------------------------------------------------------------------------
__global__ __launch_bounds__(256) void reduce_ax(const float* __restrict__ P,
                                                 float* __restrict__ AX) {
    const size_t idx = (size_t)blockIdx.x * 256 + threadIdx.x;
    const float4* P4 = (const float4*)P;
    const size_t q = CSZ / 4;
    float4 a = P4[idx], b = P4[idx + q], c = P4[idx + 2 * q], d = P4[idx + 3 * q];
    float4 r;
    r.x = a.x + b.x + c.x + d.x;
    r.y = a.y + b.y + c.y + d.y;
    r.z = a.z + b.z + c.z + d.z;
    r.w = a.w + b.w + c.w + d.w;
    ((float4*)AX)[idx] = r;
}

// ---------------------------------------------------------------------------
// Kernel 3c: weight prep. Whr[k][h][g] = Wh[k][g*32+h]; Wxr[c][h][g]; bfold.
// ---------------------------------------------------------------------------
__global__ __launch_bounds__(256) void prep_weights(const float* __restrict__ Wx,
                                                    const float* __restrict__ bx,
                                                    const float* __restrict__ Wh,
                                                    const float* __restrict__ bh,
                                                    float* __restrict__ Whr,
                                                    float* __restrict__ Wxr,
                                                    float* __restrict__ bfold) {
    const int tid = threadIdx.x;
#pragma unroll
    for (int r = 0; r < 16; ++r) {
        const int idx = tid * 16 + r;           // 4096
        const int k = idx >> 7, rem = idx & 127;
        const int h = rem >> 2, g = rem & 3;
        Whr[idx] = Wh[k * GC + g * HH + h];
    }
    {
        const int idx = tid;                    // 256
        const int c = idx >> 7, rem = idx & 127;
        const int h = rem >> 2, g = rem & 3;
        Wxr[idx] = Wx[c * GC + g * HH + h];
    }
    if (tid < 128) {
        const int h = tid >> 2, g = tid & 3;
        bfold[tid] = bx[g * HH + h] + bh[g * HH + h];
    }
}

// ---------------------------------------------------------------------------
// Group barrier: release add ONCE, RELAXED polling (no cache ops per poll),
// single acquire on exit. All 512 blocks resident (<=51KB LDS -> >=2/CU).
// ---------------------------------------------------------------------------
__device__ __forceinline__ void group_barrier(unsigned* bar) {
    __syncthreads();   // drains vmcnt: all waves' stores have reached L2
    if (threadIdx.x == 0) {
        const unsigned old = __hip_atomic_fetch_add(bar, 1u, __ATOMIC_RELEASE,
                                                    __HIP_MEMORY_SCOPE_AGENT);
        const unsigned target = (old / GBLK + 1) * GBLK;
        unsigned spins = 0;
        while (__hip_atomic_load(bar, __ATOMIC_RELAXED, __HIP_MEMORY_SCOPE_AGENT) < target
               && spins < (1u << 22)) {
            __builtin_amdgcn_s_sleep(1);
            ++spins;
        }
        (void)__hip_atomic_load(bar, __ATOMIC_ACQUIRE, __HIP_MEMORY_SCOPE_AGENT);
    }
    __syncthreads();
}

// ---------------------------------------------------------------------------
// Kernel 4: batch-partitioned persistent chains. 16 groups x 32 blocks;
// group g owns batches {2g, 2g+1}. Per block per step:
//   gemm: 64-node x 64-col tile over FULL K=2048 (BK=64, LDS dbuf, r8 skeleton)
//   acc -> LDS (ah2), __syncthreads, fused gate/LSTM for the SAME 64 nodes
//   (c-state in registers, weights LDS-resident), write hT, group_barrier.
// Only 1 barrier/step, 32 members, chains drift independently.
// ---------------------------------------------------------------------------
__global__ __launch_bounds__(256) void chain_loop(
        const _Float16* __restrict__ A2,
        const float* __restrict__ AX,
        const float* __restrict__ Whr,
        const float* __restrict__ Wxr,
        const float* __restrict__ bfold,
        float* __restrict__ h32,
        _Float16* __restrict__ hT,
        unsigned* __restrict__ bars) {
    __shared__ char smem[32768];       // 2 x 16KB gemm dbuf; ah2 (64x65 f32) overlays
    __shared__ float whr[4096];
    __shared__ float wxr[256];
    __shared__ float bfl[128];

    const int tid = threadIdx.x;
    const int g  = blockIdx.x >> 5;          // group 0..15
    const int m0 = (blockIdx.x & 31) * 64;   // node slab (gemm rows == gate nodes)
    unsigned* bar = bars + g * 32;           // 128B-strided counters

    // ---- stage LSTM weights ONCE ----
#pragma unroll
    for (int r = 0; r < 4; ++r)
        *(float4*)&whr[tid * 4 + r * 1024] = *(const float4*)&Whr[tid * 4 + r * 1024];
    if (tid < 64) *(float4*)&wxr[tid * 4] = *(const float4*)&Wxr[tid * 4];
    if (tid < 32) *(float4*)&bfl[tid * 4] = *(const float4*)&bfold[tid * 4];

    // ---- gemm staging setup: BK=64, 8 planes x 64 rows x 16B per operand ----
    const int srow = tid & 63, spl = tid >> 6;     // staging row/plane
    const _Float16* gA0 = A2 + (size_t)(m0 + srow) * 2048 + spl * 8;
    const _Float16* gA1 = A2 + (size_t)(m0 + srow) * 2048 + (4 + spl) * 8;
    const _Float16* gB0 = hT + (size_t)(g * 64 + srow) * 2048 + spl * 8;
    const _Float16* gB1 = hT + (size_t)(g * 64 + srow) * 2048 + (4 + spl) * 8;
    const int ldA0 = spl * 1024 + srow * 16;
    const int ldA1 = (4 + spl) * 1024 + srow * 16;
    const int ldB0 = 8192 + spl * 1024 + srow * 16;
    const int ldB1 = 8192 + (4 + spl) * 1024 + srow * 16;

    const int w = tid >> 6, lane = tid & 63;
    const int lrow = lane & 31, lg = lane >> 5;
    const int wr = (w >> 1) * 32;            // wave tile 32x32
    const int wc = (w & 1) * 32;
    int aoff[4], boff[4];
#pragma unroll
    for (int kk = 0; kk < 4; ++kk) {
        aoff[kk] = (2 * kk + lg) * 1024 + (wr + lrow) * 16;
        boff[kk] = 8192 + (2 * kk + lg) * 1024 + (wc + lrow) * 16;
    }

    // ---- gate setup ----
    const int nl = tid & 63;                 // node within slab
    const int hq = tid >> 6;                 // h-octet
    float* ah2 = (float*)smem;               // [64][65] f32, written post-gemm
    float creg[2][8];
#pragma unroll
    for (int bi = 0; bi < 2; ++bi)
#pragma unroll
        for (int u = 0; u < 8; ++u) creg[bi][u] = 0.0f;

    __syncthreads();

#pragma unroll 1
    for (int t = 0; t < TT; ++t) {
        // ============ phase A (t>0): gemm 64x64 over K=2048 =============
        if (t > 0) {
            const _Float16 *pa0 = gA0, *pa1 = gA1, *pb0 = gB0, *pb1 = gB1;
            f32x16 acc = (f32x16)(0.0f);
            uint4 Xa0, Xa1, Xb0, Xb1, Ya0, Ya1, Yb0, Yb1;

#define CLOAD(Q)                                                               \
    Q##a0 = *(const uint4*)pa0; pa0 += 64;                                     \
    Q##a1 = *(const uint4*)pa1; pa1 += 64;                                     \
    Q##b0 = *(const uint4*)pb0; pb0 += 64;                                     \
    Q##b1 = *(const uint4*)pb1; pb1 += 64;
#define CSTORE(Q, SB)                                                          \
    *(uint4*)((SB) + ldA0) = Q##a0;                                            \
    *(uint4*)((SB) + ldA1) = Q##a1;                                            \
    *(uint4*)((SB) + ldB0) = Q##b0;                                            \
    *(uint4*)((SB) + ldB1) = Q##b1;
#define CCOMP(BUFI) do {                                                       \
    const char* sb = smem + (BUFI) * 16384;                                    \
    _Pragma("unroll") for (int kk = 0; kk < 4; ++kk) {                         \
        f16x8 fa = *(const f16x8*)(sb + aoff[kk]);                             \
        f16x8 fb = *(const f16x8*)(sb + boff[kk]);                             \
        acc = __builtin_amdgcn_mfma_f32_32x32x16_f16(fa, fb, acc, 0, 0, 0);    \
    }                                                                          \
} while (0)

            CLOAD(X)
            CLOAD(Y)
#pragma unroll 1
            for (int it = 0; it < CNIT; it += 2) {
                CSTORE(X, smem)
                __syncthreads();
                if (it + 2 < CNIT) { CLOAD(X) }
                CCOMP(0);
                CSTORE(Y, smem + 16384)
                __syncthreads();
                if (it + 3 < CNIT) { CLOAD(Y) }
                CCOMP(1);
            }
#undef CLOAD
#undef CSTORE
#undef CCOMP
            // acc -> ah2 (LDS). Wait for all waves' last compute first.
            __syncthreads();
#pragma unroll
            for (int r = 0; r < 16; ++r) {
                const int rp = (r & 3) + 8 * (r >> 2) + 4 * lg;
                ah2[(wr + rp) * 65 + wc + lrow] = acc[r];
            }
            __syncthreads();
        }

        // ============ phase B: fused gates + cell update =================
#pragma unroll 1
        for (int bi = 0; bi < 2; ++bi) {
            const int b = 2 * g + bi;
            const float ax0 = AX[(size_t)(m0 + nl) * XCOLS + (b * TT + t) * CIN + 0];
            const float ax1 = AX[(size_t)(m0 + nl) * XCOLS + (b * TT + t) * CIN + 1];
            float acc[8][4];
#pragma unroll
            for (int u = 0; u < 8; ++u) {
                const int h = hq * 8 + u;
#pragma unroll
                for (int q4 = 0; q4 < 4; ++q4)
                    acc[u][q4] = bfl[h * 4 + q4] + ax0 * wxr[h * 4 + q4] + ax1 * wxr[128 + h * 4 + q4];
            }
            if (t > 0) {
                float ah_r[HH];
#pragma unroll
                for (int k = 0; k < HH; ++k) ah_r[k] = ah2[nl * 65 + bi * 32 + k];
#pragma unroll 4
                for (int k = 0; k < HH; ++k) {
                    const float a = ah_r[k];
#pragma unroll
                    for (int u = 0; u < 8; ++u) {
                        const float* wp = &whr[(k * HH + hq * 8 + u) * 4];
                        acc[u][0] += a * wp[0];
                        acc[u][1] += a * wp[1];
                        acc[u][2] += a * wp[2];
                        acc[u][3] += a * wp[3];
                    }
                }
            }

            float hn[8];
#pragma unroll
            for (int u = 0; u < 8; ++u) {
                const float i_ = 1.0f / (1.0f + expf(-acc[u][0]));
                const float f_ = 1.0f / (1.0f + expf(-acc[u][1]));
                const float o_ = 1.0f / (1.0f + expf(-acc[u][2]));
                const float g_ = tanhf(acc[u][3]);
                const float c_t = f_ * creg[bi][u] + i_ * g_;
                creg[bi][u] = c_t;
                hn[u] = o_ * tanhf(c_t);
            }
#pragma unroll
            for (int u = 0; u < 8; ++u)
                hT[(size_t)(b * HH + hq * 8 + u) * 2048 + m0 + nl] = (_Float16)hn[u];
            if (t == TT - 1) {
                const size_t off = (size_t)(m0 + nl) * HCOLS + b * HH + hq * 8;
                *(float4*)(h32 + off)     = make_float4(hn[0], hn[1], hn[2], hn[3]);
                *(float4*)(h32 + off + 4) = make_float4(hn[4], hn[5], hn[6], hn[7]);
            }
        }
        if (t < TT - 1) group_barrier(bar);
    }
}

// ---------------------------------------------------------------------------
// Kernel 5: out[b][th][n] = bp[th] + sum_k h[n][b*H+k] * Wp[k][th]
// ---------------------------------------------------------------------------
__global__ __launch_bounds__(256) void head_kernel(const float* __restrict__ h,
                                                   const float* __restrict__ Wp,
                                                   const float* __restrict__ bp,
                                                   float* __restrict__ out) {
    const int idx = blockIdx.x * 256 + threadIdx.x;
    const int b = idx >> 11;
    const int n = idx & (NN - 1);
    float hv[HH];
    const float* hp = h + (size_t)n * HCOLS + b * HH;
#pragma unroll
    for (int k = 0; k < HH; ++k) hv[k] = hp[k];
#pragma unroll
    for (int th = 0; th < HOR; ++th) {
        float acc = bp[th];
#pragma unroll
        for (int k = 0; k < HH; ++k) acc += hv[k] * Wp[k * HOR + th];
        out[((size_t)b * HOR + th) * NN + n] = acc;
    }
}

// ---------------------------------------------------------------------------
extern "C" void kernel_launch(void* const* d_in, const int* in_sizes, int n_in,
                              void* d_out, int out_size, void* d_ws, size_t ws_size,
                              hipStream_t stream) {
    const float* x  = (const float*)d_in[0];
    const float* E1 = (const float*)d_in[1];
    const float* E2 = (const float*)d_in[2];
    const float* Wx = (const float*)d_in[3];
    const float* bx = (const float*)d_in[4];
    const float* Wh = (const float*)d_in[5];
    const float* bh = (const float*)d_in[6];
    const float* Wp = (const float*)d_in[7];
    const float* bp = (const float*)d_in[8];

    char* ws = (char*)d_ws;
    _Float16* A2  = (_Float16*)(ws);                    //  8 MB  [2048][2048]
    _Float16* B2x = (_Float16*)(ws + ( 8ull << 20));    //  8 MB  [1024][2][2048]
    _Float16* hT  = (_Float16*)(ws + (16ull << 20));    //  4 MB  [1024][2048]
    float* P    = (float*)(ws + (20ull << 20));         // 32 MB  (x-path partials)
    float* AX   = (float*)(ws + (52ull << 20));         //  8 MB
    float* h32  = (float*)(ws + (68ull << 20));         //  8 MB
    float* Whr  = (float*)(ws + (76ull << 20));         // 16 KB
    float* Wxr  = (float*)(ws + (76ull << 20) + 65536);
    float* bfold= (float*)(ws + (76ull << 20) + 131072);
    unsigned* bars = (unsigned*)(ws + (77ull << 20));   // 16 group counters, 128B stride

    hipMemsetAsync(bars, 0, 4096, stream);

    adj_softmax<<<NN, 256, 0, stream>>>(E1, E2, A2);
    transpose_x<<<(XCOLS * NN) / 256, 256, 0, stream>>>(x, B2x);
    prep_weights<<<1, 256, 0, stream>>>(Wx, bx, Wh, bh, Whr, Wxr, bfold);

    dim3 gg(HCOLS / 128, NN / 128, KSPLIT);   // 8 x 16 x 4 = 512 blocks
    gemm_x<<<gg, 256, 0, stream>>>(A2, B2x, P);          // x path: hi+lo
    reduce_ax<<<(int)(CSZ / 4 / 256), 256, 0, stream>>>(P, AX);

    // 16 independent batch-pair chains, 32 blocks each (all resident)
    chain_loop<<<NG * GBLK, 256, 0, stream>>>(A2, AX, Whr, Wxr, bfold, h32, hT, bars);

    head_kernel<<<(BB * NN) / 256, 256, 0, stream>>>(h32, Wp, bp, (float*)d_out);
}